// Round 7
// baseline (266.963 us; speedup 1.0000x reference)
//
#include <hip/hip_runtime.h>

#define C_CH 16
#define DIM 48
#define P_TOT (48 * 48 * 48 * 48)  // 5308416
#define QSCALE (127.0f / 8.0f)
#define QINV   (8.0f / 127.0f)

#define NQBLK (P_TOT / 256)        // 20736 quantize blocks
#define NEXP  (4 * P_TOT / 256)    // 82944 expand blocks

// ---------------- shared coordinate math ----------------
__device__ __forceinline__ void coord_1d(float r, float mn, float mx, int& lo, int& hi,
                                         float& wlo, float& whi) {
    float t     = (r - mn) / (mx - mn);
    float ind   = t * 2.0f - 1.0f;
    float coord = (ind + 1.0f) * 0.5f * (float)(DIM - 1);
    float b  = floorf(coord);
    int   bi = (int)b;
    float w  = coord - b;
    bool v0 = (bi >= 0) && (bi < DIM);
    bool v1 = (bi + 1 >= 0) && (bi + 1 < DIM);
    lo  = min(max(bi, 0), DIM - 1);
    hi  = min(max(bi + 1, 0), DIM - 1);
    wlo = v0 ? (1.0f - w) : 0.0f;
    whi = v1 ? w : 0.0f;
}

// entry-based (z,w dims of quad layout): entry e holds cells (e, e+1 clamped)
__device__ __forceinline__ void coord_1d_q(float r, float mn, float mx, int& e,
                                           float& wa, float& wb) {
    float t     = (r - mn) / (mx - mn);
    float ind   = t * 2.0f - 1.0f;
    float coord = (ind + 1.0f) * 0.5f * (float)(DIM - 1);
    float b  = floorf(coord);
    int   bi = (int)b;
    float w  = coord - b;
    bool v0 = (bi >= 0) && (bi < DIM);
    e  = min(max(bi, 0), DIM - 1);
    wa = v0 ? (1.0f - w) : ((bi == -1) ? w : 0.0f);
    wb = (v0 && (bi < DIM - 1)) ? w : 0.0f;
}

__device__ __forceinline__ int q8(float x) {
    float q = rintf(x * QSCALE);
    q = fminf(fmaxf(q, -127.0f), 127.0f);
    return (int)q;
}

// ---------------- K1 quantize: grid (C,P) f32 -> point-major int8 (16 B/point) ----------------
// Thread t = point p. 16 coalesced plane reads (64 lanes x 4 B = 256 B/line-perfect per
// instruction), pack to uint4, perfectly coalesced 16 B store. r0-proven pattern (~5.9 TB/s).
__global__ __launch_bounds__(256) void quantize_kernel(
    const float* __restrict__ grid,
    uint4* __restrict__ pts)
{
    int t = blockIdx.x * 256 + threadIdx.x;
    if (t >= P_TOT) return;

    unsigned int pk[4];
#pragma unroll
    for (int j = 0; j < 4; ++j) {
        unsigned int b0 = (unsigned int)(q8(grid[(size_t)(4 * j + 0) * P_TOT + t]) & 0xFF);
        unsigned int b1 = (unsigned int)(q8(grid[(size_t)(4 * j + 1) * P_TOT + t]) & 0xFF);
        unsigned int b2 = (unsigned int)(q8(grid[(size_t)(4 * j + 2) * P_TOT + t]) & 0xFF);
        unsigned int b3 = (unsigned int)(q8(grid[(size_t)(4 * j + 3) * P_TOT + t]) & 0xFF);
        pk[j] = b0 | (b1 << 8) | (b2 << 16) | (b3 << 24);
    }
    pts[t] = make_uint4(pk[0], pk[1], pk[2], pk[3]);
}

// ---------------- K2 expand: point-major int8 -> quad layout ----------------
// Quad entry e = ((x*48+y)*48+z)*48+w, 64 B: cells k=(zl<<1)|wl at (z+zl clamp, w+wl clamp).
// 4 threads per entry: thread u copies point (z+dz, w+dw) -> quarter k of entry u>>2.
// Reads: two ~272 B contiguous segments per wave from an 85 MB L2/L3-hot set (4x logical
// reuse absorbed); writes: perfectly contiguous uint4 stream (write-rate bound).
__global__ __launch_bounds__(256) void expand_quad_kernel(
    const uint4* __restrict__ pts,
    uint4* __restrict__ ws)
{
    int bid = (int)blockIdx.x;
    bid = (bid & 7) * (NEXP >> 3) + (bid >> 3);   // bijective XCD chunking (NEXP % 8 == 0)
    int u = bid * 256 + (int)threadIdx.x;

    int k = u & 3;
    int e = u >> 2;
    int w = e % DIM;
    int z = (e / DIM) % DIM;

    int dz = k >> 1;
    if (z + dz >= DIM) dz = 0;                    // clamp (weight-0 duplicate)
    int dw = k & 1;
    if (w + dw >= DIM) dw = 0;

    ws[u] = pts[e + dz * DIM + dw];
}

// ---------------- int8 cell accumulate ----------------
__device__ __forceinline__ void accum_cell(const uint4& cell, float wc, float* acc) {
#pragma unroll
    for (int j = 0; j < 4; ++j) {
        unsigned int u = (&cell.x)[j];
        acc[4 * j + 0] += (float)((int)(u << 24) >> 24) * wc;
        acc[4 * j + 1] += (float)((int)(u << 16) >> 24) * wc;
        acc[4 * j + 2] += (float)((int)(u <<  8) >> 24) * wc;
        acc[4 * j + 3] += (float)((int)u         >> 24) * wc;
    }
}

// ---------------- gather: quad layout, 4 contiguous 64B entries per ray ----------------
__global__ __launch_bounds__(256) void gather_quad_kernel(
    const float4* __restrict__ ray,
    const uint4* __restrict__ gq,
    const float* __restrict__ ray_min,
    const float* __restrict__ ray_max,
    float* __restrict__ out,
    int n_rays)
{
    int n = blockIdx.x * 256 + threadIdx.x;
    if (n >= n_rays) return;

    float4 r4 = ray[n];

    int   i0x, i1x, i0y, i1y;
    float w0x, w1x, w0y, w1y;
    coord_1d(r4.x, ray_min[0], ray_max[0], i0x, i1x, w0x, w1x);
    coord_1d(r4.y, ray_min[1], ray_max[1], i0y, i1y, w0y, w1y);

    int ez, ew;
    float waz, wbz, waw, wbw;
    coord_1d_q(r4.z, ray_min[2], ray_max[2], ez, waz, wbz);
    coord_1d_q(r4.w, ray_min[3], ray_max[3], ew, waw, wbw);

    float wzw[4];
    wzw[0] = waz * waw;
    wzw[1] = waz * wbw;
    wzw[2] = wbz * waw;
    wzw[3] = wbz * wbw;

    float acc[C_CH];
#pragma unroll
    for (int c = 0; c < C_CH; ++c) acc[c] = 0.0f;

    int ezw = ez * DIM + ew;

#pragma unroll
    for (int cx = 0; cx < 2; ++cx) {
        int   x  = cx ? i1x : i0x;
        float fx = (cx ? w1x : w0x) * QINV;
#pragma unroll
        for (int cy = 0; cy < 2; ++cy) {
            int   y   = cy ? i1y : i0y;
            float fxy = fx * (cy ? w1y : w0y);
            int ebase = ((x * DIM + y) * (DIM * DIM) + ezw) << 2;
            uint4 c0 = gq[ebase + 0];
            uint4 c1 = gq[ebase + 1];
            uint4 c2 = gq[ebase + 2];
            uint4 c3 = gq[ebase + 3];
            accum_cell(c0, fxy * wzw[0], acc);
            accum_cell(c1, fxy * wzw[1], acc);
            accum_cell(c2, fxy * wzw[2], acc);
            accum_cell(c3, fxy * wzw[3], acc);
        }
    }

    float4* o = reinterpret_cast<float4*>(out + (size_t)n * C_CH);
    o[0] = make_float4(acc[0],  acc[1],  acc[2],  acc[3]);
    o[1] = make_float4(acc[4],  acc[5],  acc[6],  acc[7]);
    o[2] = make_float4(acc[8],  acc[9],  acc[10], acc[11]);
    o[3] = make_float4(acc[12], acc[13], acc[14], acc[15]);
}

// ---------------- mid fallback: tiled int8 (2x2x2 of y,z,w), 16 B per cell ----------------
__global__ __launch_bounds__(256) void convert_tiled_kernel(
    const float* __restrict__ grid,
    uint4* __restrict__ ws)
{
    int t = blockIdx.x * 256 + threadIdx.x;
    if (t >= P_TOT) return;

    int intra = t & 7;
    int line  = t >> 3;
    int wh = line % 24;  int r1 = line / 24;
    int zh = r1 % 24;    int r2 = r1 / 24;
    int yh = r2 % 24;    int x  = r2 / 24;
    int wl = intra & 1, zl = (intra >> 1) & 1, yl = (intra >> 2) & 1;
    int y = yh * 2 + yl, z = zh * 2 + zl, w = wh * 2 + wl;
    int p = ((x * DIM + y) * DIM + z) * DIM + w;

    unsigned int pk[4];
#pragma unroll
    for (int j = 0; j < 4; ++j) {
        unsigned int b0 = (unsigned int)(q8(grid[(size_t)(4 * j + 0) * P_TOT + p]) & 0xFF);
        unsigned int b1 = (unsigned int)(q8(grid[(size_t)(4 * j + 1) * P_TOT + p]) & 0xFF);
        unsigned int b2 = (unsigned int)(q8(grid[(size_t)(4 * j + 2) * P_TOT + p]) & 0xFF);
        unsigned int b3 = (unsigned int)(q8(grid[(size_t)(4 * j + 3) * P_TOT + p]) & 0xFF);
        pk[j] = b0 | (b1 << 8) | (b2 << 16) | (b3 << 24);
    }
    ws[t] = make_uint4(pk[0], pk[1], pk[2], pk[3]);
}

__global__ __launch_bounds__(256) void gather_tiled_kernel(
    const float4* __restrict__ ray,
    const uint4* __restrict__ gq,
    const float* __restrict__ ray_min,
    const float* __restrict__ ray_max,
    float* __restrict__ out,
    int n_rays)
{
    int n = blockIdx.x * 256 + threadIdx.x;
    if (n >= n_rays) return;

    float4 r4 = ray[n];
    float rr[4] = {r4.x, r4.y, r4.z, r4.w};

    int   i0[4], i1[4];
    float w0[4], w1[4];
#pragma unroll
    for (int d = 0; d < 4; ++d)
        coord_1d(rr[d], ray_min[d], ray_max[d], i0[d], i1[d], w0[d], w1[d]);

    float acc[C_CH];
#pragma unroll
    for (int c = 0; c < C_CH; ++c) acc[c] = 0.0f;

#pragma unroll
    for (int cx = 0; cx < 2; ++cx) {
        int   x  = cx ? i1[0] : i0[0];
        float fx = (cx ? w1[0] : w0[0]) * QINV;
        int bx = x * 24;
#pragma unroll
        for (int cy = 0; cy < 2; ++cy) {
            int   y   = cy ? i1[1] : i0[1];
            float fxy = fx * (cy ? w1[1] : w0[1]);
            int ly = (bx + (y >> 1)) * 24;
            int iy = (y & 1) << 2;
#pragma unroll
            for (int cz = 0; cz < 2; ++cz) {
                int   z    = cz ? i1[2] : i0[2];
                float fxyz = fxy * (cz ? w1[2] : w0[2]);
                int lz = (ly + (z >> 1)) * 24;
                int iz = iy | ((z & 1) << 1);
#pragma unroll
                for (int cw = 0; cw < 2; ++cw) {
                    int   w  = cw ? i1[3] : i0[3];
                    float wc = fxyz * (cw ? w1[3] : w0[3]);
                    int cellidx = ((lz + (w >> 1)) << 3) | iz | (w & 1);
                    uint4 cell = gq[cellidx];
                    accum_cell(cell, wc, acc);
                }
            }
        }
    }

    float4* o = reinterpret_cast<float4*>(out + (size_t)n * C_CH);
    o[0] = make_float4(acc[0],  acc[1],  acc[2],  acc[3]);
    o[1] = make_float4(acc[4],  acc[5],  acc[6],  acc[7]);
    o[2] = make_float4(acc[8],  acc[9],  acc[10], acc[11]);
    o[3] = make_float4(acc[12], acc[13], acc[14], acc[15]);
}

// ---------------- f32 fallback if ws too small ----------------
__global__ __launch_bounds__(256) void lf4d_gather_kernel(
    const float4* __restrict__ ray,
    const float* __restrict__ grid,
    const float* __restrict__ ray_min,
    const float* __restrict__ ray_max,
    float* __restrict__ out,
    int n_rays)
{
    int n = blockIdx.x * 256 + threadIdx.x;
    if (n >= n_rays) return;
    float4 r4 = ray[n];
    float rr[4] = {r4.x, r4.y, r4.z, r4.w};
    int   i0[4], i1[4];
    float w0[4], w1[4];
#pragma unroll
    for (int d = 0; d < 4; ++d)
        coord_1d(rr[d], ray_min[d], ray_max[d], i0[d], i1[d], w0[d], w1[d]);
    float acc[C_CH];
#pragma unroll
    for (int c = 0; c < C_CH; ++c) acc[c] = 0.0f;
    const int s0 = DIM * DIM * DIM, s1 = DIM * DIM, s2 = DIM;
#pragma unroll
    for (int k = 0; k < 8; ++k) {
        int   x  = (k & 1) ? i1[0] : i0[0];
        float wx = (k & 1) ? w1[0] : w0[0];
        int   y  = (k & 2) ? i1[1] : i0[1];
        float wy = (k & 2) ? w1[1] : w0[1];
        int   z  = (k & 4) ? i1[2] : i0[2];
        float wz = (k & 4) ? w1[2] : w0[2];
        int   base = x * s0 + y * s1 + z * s2;
        float wxyz = wx * wy * wz;
        float wa = wxyz * w0[3], wb = wxyz * w1[3];
        int ia = base + i0[3], ib = base + i1[3];
#pragma unroll
        for (int c = 0; c < C_CH; ++c) {
            float va = grid[c * P_TOT + ia];
            float vb = grid[c * P_TOT + ib];
            acc[c] += va * wa + vb * wb;
        }
    }
    float4* o = reinterpret_cast<float4*>(out + (size_t)n * C_CH);
    o[0] = make_float4(acc[0],  acc[1],  acc[2],  acc[3]);
    o[1] = make_float4(acc[4],  acc[5],  acc[6],  acc[7]);
    o[2] = make_float4(acc[8],  acc[9],  acc[10], acc[11]);
    o[3] = make_float4(acc[12], acc[13], acc[14], acc[15]);
}

static inline size_t align256(size_t x) { return (x + 255) & ~(size_t)255; }

extern "C" void kernel_launch(void* const* d_in, const int* in_sizes, int n_in,
                              void* d_out, int out_size, void* d_ws, size_t ws_size,
                              hipStream_t stream) {
    const float4* ray     = (const float4*)d_in[0];
    const float*  grid    = (const float*)d_in[1];
    const float*  ray_min = (const float*)d_in[2];
    const float*  ray_max = (const float*)d_in[3];
    float*        out     = (float*)d_out;

    int n_rays  = in_sizes[0] / 4;
    int rblocks = (n_rays + 255) / 256;

    const size_t quad_bytes  = (size_t)P_TOT * 64;   // ~340 MiB
    const size_t pts_bytes   = (size_t)P_TOT * 16;   // ~81 MiB
    const size_t pts_off     = align256(quad_bytes);
    const size_t need_full   = pts_off + pts_bytes;  // ~425 MiB
    const size_t tiled_bytes = (size_t)P_TOT * 16;

    if (ws_size >= need_full) {
        uint4* gq  = (uint4*)d_ws;
        uint4* pts = (uint4*)((char*)d_ws + pts_off);
        quantize_kernel<<<NQBLK, 256, 0, stream>>>(grid, pts);
        expand_quad_kernel<<<NEXP, 256, 0, stream>>>(pts, gq);
        gather_quad_kernel<<<rblocks, 256, 0, stream>>>(
            ray, (const uint4*)gq, ray_min, ray_max, out, n_rays);
    } else if (ws_size >= tiled_bytes) {
        uint4* gq = (uint4*)d_ws;
        int tblocks = (P_TOT + 255) / 256;
        convert_tiled_kernel<<<tblocks, 256, 0, stream>>>(grid, gq);
        gather_tiled_kernel<<<rblocks, 256, 0, stream>>>(
            ray, (const uint4*)gq, ray_min, ray_max, out, n_rays);
    } else {
        lf4d_gather_kernel<<<rblocks, 256, 0, stream>>>(ray, grid, ray_min, ray_max, out, n_rays);
    }
}

// Round 8
// 200.821 us; speedup vs baseline: 1.3294x; 1.3294x over previous
//
#include <hip/hip_runtime.h>

#define C_CH 16
#define DIM 48
#define P_TOT (48 * 48 * 48 * 48)  // 5308416
#define QSCALE (127.0f / 8.0f)
#define QINV   (8.0f / 127.0f)

#define ZB    16                  // z-rows per convert block (no overlap: z-pairing is intra-slab)
#define WST   49                  // LDS cell stride per row (breaks power-of-2 wrap)
#define ZBLKS (DIM / ZB)          // 3
#define NCONV (DIM * DIM * ZBLKS) // 6912 blocks

// LDS cell-position swizzle: involution, spreads bank usage of stride-4(w) access
__device__ __forceinline__ int lds_swz(int A) { return A ^ ((A >> 2) & 3); }

// ---------------- shared coordinate math ----------------
__device__ __forceinline__ void coord_1d(float r, float mn, float mx, int& lo, int& hi,
                                         float& wlo, float& whi) {
    float t     = (r - mn) / (mx - mn);
    float ind   = t * 2.0f - 1.0f;
    float coord = (ind + 1.0f) * 0.5f * (float)(DIM - 1);
    float b  = floorf(coord);
    int   bi = (int)b;
    float w  = coord - b;
    bool v0 = (bi >= 0) && (bi < DIM);
    bool v1 = (bi + 1 >= 0) && (bi + 1 < DIM);
    lo  = min(max(bi, 0), DIM - 1);
    hi  = min(max(bi + 1, 0), DIM - 1);
    wlo = v0 ? (1.0f - w) : 0.0f;
    whi = v1 ? w : 0.0f;
}

// entry-based (w dim of duo layout): entry holds cells (e, e+1 clamped)
__device__ __forceinline__ void coord_1d_q(float r, float mn, float mx, int& e,
                                           float& wa, float& wb) {
    float t     = (r - mn) / (mx - mn);
    float ind   = t * 2.0f - 1.0f;
    float coord = (ind + 1.0f) * 0.5f * (float)(DIM - 1);
    float b  = floorf(coord);
    int   bi = (int)b;
    float w  = coord - b;
    bool v0 = (bi >= 0) && (bi < DIM);
    e  = min(max(bi, 0), DIM - 1);
    wa = v0 ? (1.0f - w) : ((bi == -1) ? w : 0.0f);
    wb = (v0 && (bi < DIM - 1)) ? w : 0.0f;
}

__device__ __forceinline__ int q8(float x) {
    float q = rintf(x * QSCALE);
    q = fminf(fmaxf(q, -127.0f), 127.0f);
    return (int)q;
}

__device__ __forceinline__ unsigned int pack4(float a, float b, float c, float d) {
    return  (unsigned int)(q8(a) & 0xFF)
         | ((unsigned int)(q8(b) & 0xFF) << 8)
         | ((unsigned int)(q8(c) & 0xFF) << 16)
         | ((unsigned int)(q8(d) & 0xFF) << 24);
}

// ---------------- fused convert: grid (C,P) f32 -> duo-w/paired-z int8 layout ----------------
// 64-B line L = ((x*48+y)*24 + zh)*48 + ew holds 4 cells:
//   uint4 sub s = (zc&1)*2 + dw  ->  cell (z = 2*zh + (zc&1), w = min(ew+dw,47)), 16 int8 ch.
// Storage 2x (170 MB). Stage 1 = r4's proven loader (cq-fastest, swizzled b32 LDS writes).
// Stage 2: compose lines from LDS, perfectly coalesced contiguous uint4 stores.
__global__ __launch_bounds__(256) void convert_duo_lds_kernel(
    const float* __restrict__ grid,
    uint4* __restrict__ ws)
{
    // bijective XCD-chunk swizzle: NCONV % 8 == 0
    int bid = (int)blockIdx.x;
    bid = (bid & 7) * (NCONV >> 3) + (bid >> 3);

    int zb = bid % ZBLKS;
    int xy = bid / ZBLKS;
    int y  = xy % DIM;
    int x  = xy / DIM;
    int z0 = zb * ZB;
    int xy48 = (x * DIM + y) * DIM;

    __shared__ uint4 qv[ZB * WST];             // 12544 B
    unsigned int* qw = (unsigned int*)qv;

    // ---- stage 1: items (ri, wq, cq), cq fastest; 3072 = 256*12 exactly ----
    const int NITEM = ZB * 12 * 4;
    for (int it = (int)threadIdx.x; it < NITEM; it += 256) {
        int cq = it & 3;
        int t1 = it >> 2;
        int wq = t1 % 12;
        int ri = t1 / 12;                      // 0..15, zg always in range
        int zg = z0 + ri;

        const float* gp = grid + (size_t)(4 * cq) * P_TOT
                               + (size_t)(xy48 + zg) * DIM + 4 * wq;
        float4 v0 = *(const float4*)(gp);
        float4 v1 = *(const float4*)(gp + (size_t)P_TOT);
        float4 v2 = *(const float4*)(gp + (size_t)2 * P_TOT);
        float4 v3 = *(const float4*)(gp + (size_t)3 * P_TOT);

        unsigned int wd0 = pack4(v0.x, v1.x, v2.x, v3.x);
        unsigned int wd1 = pack4(v0.y, v1.y, v2.y, v3.y);
        unsigned int wd2 = pack4(v0.z, v1.z, v2.z, v3.z);
        unsigned int wd3 = pack4(v0.w, v1.w, v2.w, v3.w);

        int Abase = ri * WST + 4 * wq;
        qw[lds_swz(Abase + 0) * 4 + cq] = wd0;
        qw[lds_swz(Abase + 1) * 4 + cq] = wd1;
        qw[lds_swz(Abase + 2) * 4 + cq] = wd2;
        qw[lds_swz(Abase + 3) * 4 + cq] = wd3;
    }
    __syncthreads();

    // ---- stage 2: compose duo lines, contiguous coalesced 16B stores ----
    const int NOUT = (ZB / 2) * DIM * 4;       // 1536 uint4
    size_t ubase = (size_t)((x * DIM + y) * (DIM / 2) + (z0 >> 1)) * (DIM * 4);
    for (int idx = (int)threadIdx.x; idx < NOUT; idx += 256) {
        int zh_loc = idx / 192;                // 192 = 48*4
        int r      = idx - zh_loc * 192;
        int ew     = r >> 2;
        int sub    = r & 3;
        int zc_loc = (zh_loc << 1) | (sub >> 1);
        int wsrc   = min(ew + (sub & 1), DIM - 1);
        int A      = zc_loc * WST + wsrc;
        ws[ubase + idx] = qv[lds_swz(A)];
    }
}

// ---------------- int8 cell accumulate ----------------
__device__ __forceinline__ void accum_cell(const uint4& cell, float wc, float* acc) {
#pragma unroll
    for (int j = 0; j < 4; ++j) {
        unsigned int u = (&cell.x)[j];
        acc[4 * j + 0] += (float)((int)(u << 24) >> 24) * wc;
        acc[4 * j + 1] += (float)((int)(u << 16) >> 24) * wc;
        acc[4 * j + 2] += (float)((int)(u <<  8) >> 24) * wc;
        acc[4 * j + 3] += (float)((int)u         >> 24) * wc;
    }
}

// ---------------- gather: duo layout, 6 expected 64B lines per ray ----------------
__global__ __launch_bounds__(256) void gather_duo_kernel(
    const float4* __restrict__ ray,
    const uint4* __restrict__ gq,
    const float* __restrict__ ray_min,
    const float* __restrict__ ray_max,
    float* __restrict__ out,
    int n_rays)
{
    int n = blockIdx.x * 256 + threadIdx.x;
    if (n >= n_rays) return;

    float4 r4 = ray[n];

    int   i0x, i1x, i0y, i1y, i0z, i1z;
    float w0x, w1x, w0y, w1y, w0z, w1z;
    coord_1d(r4.x, ray_min[0], ray_max[0], i0x, i1x, w0x, w1x);
    coord_1d(r4.y, ray_min[1], ray_max[1], i0y, i1y, w0y, w1y);
    coord_1d(r4.z, ray_min[2], ray_max[2], i0z, i1z, w0z, w1z);

    int ew;
    float waw, wbw;
    coord_1d_q(r4.w, ray_min[3], ray_max[3], ew, waw, wbw);

    int zo0 = (i0z >> 1) * (DIM * 4) + (ew << 2) + ((i0z & 1) << 1);
    int zo1 = (i1z >> 1) * (DIM * 4) + (ew << 2) + ((i1z & 1) << 1);

    float acc[C_CH];
#pragma unroll
    for (int c = 0; c < C_CH; ++c) acc[c] = 0.0f;

#pragma unroll
    for (int cx = 0; cx < 2; ++cx) {
        int   x  = cx ? i1x : i0x;
        float fx = (cx ? w1x : w0x) * QINV;   // fold int8 scale into weight
#pragma unroll
        for (int cy = 0; cy < 2; ++cy) {
            int   y   = cy ? i1y : i0y;
            float fxy = fx * (cy ? w1y : w0y);
            int lb = (x * DIM + y) * (DIM / 2) * (DIM * 4);  // uint4 base of (x,y) panel

            int u0 = lb + zo0;
            uint4 a0 = gq[u0];
            uint4 b0 = gq[u0 + 1];
            float f0 = fxy * w0z;
            accum_cell(a0, f0 * waw, acc);
            accum_cell(b0, f0 * wbw, acc);

            int u1 = lb + zo1;
            uint4 a1 = gq[u1];
            uint4 b1 = gq[u1 + 1];
            float f1 = fxy * w1z;
            accum_cell(a1, f1 * waw, acc);
            accum_cell(b1, f1 * wbw, acc);
        }
    }

    float4* o = reinterpret_cast<float4*>(out + (size_t)n * C_CH);
    o[0] = make_float4(acc[0],  acc[1],  acc[2],  acc[3]);
    o[1] = make_float4(acc[4],  acc[5],  acc[6],  acc[7]);
    o[2] = make_float4(acc[8],  acc[9],  acc[10], acc[11]);
    o[3] = make_float4(acc[12], acc[13], acc[14], acc[15]);
}

// ---------------- mid fallback: tiled int8 (2x2x2 of y,z,w), 16 B per cell ----------------
__global__ __launch_bounds__(256) void convert_tiled_kernel(
    const float* __restrict__ grid,
    uint4* __restrict__ ws)
{
    int t = blockIdx.x * 256 + threadIdx.x;
    if (t >= P_TOT) return;

    int intra = t & 7;
    int line  = t >> 3;
    int wh = line % 24;  int r1 = line / 24;
    int zh = r1 % 24;    int r2 = r1 / 24;
    int yh = r2 % 24;    int x  = r2 / 24;
    int wl = intra & 1, zl = (intra >> 1) & 1, yl = (intra >> 2) & 1;
    int y = yh * 2 + yl, z = zh * 2 + zl, w = wh * 2 + wl;
    int p = ((x * DIM + y) * DIM + z) * DIM + w;

    unsigned int pk[4];
#pragma unroll
    for (int j = 0; j < 4; ++j) {
        unsigned int b0 = (unsigned int)(q8(grid[(size_t)(4 * j + 0) * P_TOT + p]) & 0xFF);
        unsigned int b1 = (unsigned int)(q8(grid[(size_t)(4 * j + 1) * P_TOT + p]) & 0xFF);
        unsigned int b2 = (unsigned int)(q8(grid[(size_t)(4 * j + 2) * P_TOT + p]) & 0xFF);
        unsigned int b3 = (unsigned int)(q8(grid[(size_t)(4 * j + 3) * P_TOT + p]) & 0xFF);
        pk[j] = b0 | (b1 << 8) | (b2 << 16) | (b3 << 24);
    }
    ws[t] = make_uint4(pk[0], pk[1], pk[2], pk[3]);
}

__global__ __launch_bounds__(256) void gather_tiled_kernel(
    const float4* __restrict__ ray,
    const uint4* __restrict__ gq,
    const float* __restrict__ ray_min,
    const float* __restrict__ ray_max,
    float* __restrict__ out,
    int n_rays)
{
    int n = blockIdx.x * 256 + threadIdx.x;
    if (n >= n_rays) return;

    float4 r4 = ray[n];
    float rr[4] = {r4.x, r4.y, r4.z, r4.w};

    int   i0[4], i1[4];
    float w0[4], w1[4];
#pragma unroll
    for (int d = 0; d < 4; ++d)
        coord_1d(rr[d], ray_min[d], ray_max[d], i0[d], i1[d], w0[d], w1[d]);

    float acc[C_CH];
#pragma unroll
    for (int c = 0; c < C_CH; ++c) acc[c] = 0.0f;

#pragma unroll
    for (int cx = 0; cx < 2; ++cx) {
        int   x  = cx ? i1[0] : i0[0];
        float fx = (cx ? w1[0] : w0[0]) * QINV;
        int bx = x * 24;
#pragma unroll
        for (int cy = 0; cy < 2; ++cy) {
            int   y   = cy ? i1[1] : i0[1];
            float fxy = fx * (cy ? w1[1] : w0[1]);
            int ly = (bx + (y >> 1)) * 24;
            int iy = (y & 1) << 2;
#pragma unroll
            for (int cz = 0; cz < 2; ++cz) {
                int   z    = cz ? i1[2] : i0[2];
                float fxyz = fxy * (cz ? w1[2] : w0[2]);
                int lz = (ly + (z >> 1)) * 24;
                int iz = iy | ((z & 1) << 1);
#pragma unroll
                for (int cw = 0; cw < 2; ++cw) {
                    int   w  = cw ? i1[3] : i0[3];
                    float wc = fxyz * (cw ? w1[3] : w0[3]);
                    int cellidx = ((lz + (w >> 1)) << 3) | iz | (w & 1);
                    uint4 cell = gq[cellidx];
                    accum_cell(cell, wc, acc);
                }
            }
        }
    }

    float4* o = reinterpret_cast<float4*>(out + (size_t)n * C_CH);
    o[0] = make_float4(acc[0],  acc[1],  acc[2],  acc[3]);
    o[1] = make_float4(acc[4],  acc[5],  acc[6],  acc[7]);
    o[2] = make_float4(acc[8],  acc[9],  acc[10], acc[11]);
    o[3] = make_float4(acc[12], acc[13], acc[14], acc[15]);
}

// ---------------- f32 fallback if ws too small ----------------
__global__ __launch_bounds__(256) void lf4d_gather_kernel(
    const float4* __restrict__ ray,
    const float* __restrict__ grid,
    const float* __restrict__ ray_min,
    const float* __restrict__ ray_max,
    float* __restrict__ out,
    int n_rays)
{
    int n = blockIdx.x * 256 + threadIdx.x;
    if (n >= n_rays) return;
    float4 r4 = ray[n];
    float rr[4] = {r4.x, r4.y, r4.z, r4.w};
    int   i0[4], i1[4];
    float w0[4], w1[4];
#pragma unroll
    for (int d = 0; d < 4; ++d)
        coord_1d(rr[d], ray_min[d], ray_max[d], i0[d], i1[d], w0[d], w1[d]);
    float acc[C_CH];
#pragma unroll
    for (int c = 0; c < C_CH; ++c) acc[c] = 0.0f;
    const int s0 = DIM * DIM * DIM, s1 = DIM * DIM, s2 = DIM;
#pragma unroll
    for (int k = 0; k < 8; ++k) {
        int   x  = (k & 1) ? i1[0] : i0[0];
        float wx = (k & 1) ? w1[0] : w0[0];
        int   y  = (k & 2) ? i1[1] : i0[1];
        float wy = (k & 2) ? w1[1] : w0[1];
        int   z  = (k & 4) ? i1[2] : i0[2];
        float wz = (k & 4) ? w1[2] : w0[2];
        int   base = x * s0 + y * s1 + z * s2;
        float wxyz = wx * wy * wz;
        float wa = wxyz * w0[3], wb = wxyz * w1[3];
        int ia = base + i0[3], ib = base + i1[3];
#pragma unroll
        for (int c = 0; c < C_CH; ++c) {
            float va = grid[c * P_TOT + ia];
            float vb = grid[c * P_TOT + ib];
            acc[c] += va * wa + vb * wb;
        }
    }
    float4* o = reinterpret_cast<float4*>(out + (size_t)n * C_CH);
    o[0] = make_float4(acc[0],  acc[1],  acc[2],  acc[3]);
    o[1] = make_float4(acc[4],  acc[5],  acc[6],  acc[7]);
    o[2] = make_float4(acc[8],  acc[9],  acc[10], acc[11]);
    o[3] = make_float4(acc[12], acc[13], acc[14], acc[15]);
}

extern "C" void kernel_launch(void* const* d_in, const int* in_sizes, int n_in,
                              void* d_out, int out_size, void* d_ws, size_t ws_size,
                              hipStream_t stream) {
    const float4* ray     = (const float4*)d_in[0];
    const float*  grid    = (const float*)d_in[1];
    const float*  ray_min = (const float*)d_in[2];
    const float*  ray_max = (const float*)d_in[3];
    float*        out     = (float*)d_out;

    int n_rays  = in_sizes[0] / 4;
    int rblocks = (n_rays + 255) / 256;

    const size_t duo_bytes   = (size_t)P_TOT * 32;  // ~170 MiB
    const size_t tiled_bytes = (size_t)P_TOT * 16;  // ~81 MiB

    if (ws_size >= duo_bytes) {
        uint4* gq = (uint4*)d_ws;
        convert_duo_lds_kernel<<<NCONV, 256, 0, stream>>>(grid, gq);
        gather_duo_kernel<<<rblocks, 256, 0, stream>>>(
            ray, (const uint4*)gq, ray_min, ray_max, out, n_rays);
    } else if (ws_size >= tiled_bytes) {
        uint4* gq = (uint4*)d_ws;
        int tblocks = (P_TOT + 255) / 256;
        convert_tiled_kernel<<<tblocks, 256, 0, stream>>>(grid, gq);
        gather_tiled_kernel<<<rblocks, 256, 0, stream>>>(
            ray, (const uint4*)gq, ray_min, ray_max, out, n_rays);
    } else {
        lf4d_gather_kernel<<<rblocks, 256, 0, stream>>>(ray, grid, ray_min, ray_max, out, n_rays);
    }
}

// Round 9
// 189.867 us; speedup vs baseline: 1.4061x; 1.0577x over previous
//
#include <hip/hip_runtime.h>

#define C_CH 16
#define DIM 48
#define P_TOT (48 * 48 * 48 * 48)  // 5308416
#define QSCALE (127.0f / 8.0f)
#define QINV   (8.0f / 127.0f)

#define ZB    16                  // z-rows per convert block (no overlap: z-pairing is intra-slab)
#define WST   49                  // LDS cell stride per row (breaks power-of-2 wrap)
#define ZBLKS (DIM / ZB)          // 3
#define NCONV (DIM * DIM * ZBLKS) // 6912 blocks

typedef float f32x4 __attribute__((ext_vector_type(4)));

// LDS cell-position swizzle: involution, spreads bank usage of stride-4(w) access
__device__ __forceinline__ int lds_swz(int A) { return A ^ ((A >> 2) & 3); }

// ---------------- shared coordinate math ----------------
__device__ __forceinline__ void coord_1d(float r, float mn, float mx, int& lo, int& hi,
                                         float& wlo, float& whi) {
    float t     = (r - mn) / (mx - mn);
    float ind   = t * 2.0f - 1.0f;
    float coord = (ind + 1.0f) * 0.5f * (float)(DIM - 1);
    float b  = floorf(coord);
    int   bi = (int)b;
    float w  = coord - b;
    bool v0 = (bi >= 0) && (bi < DIM);
    bool v1 = (bi + 1 >= 0) && (bi + 1 < DIM);
    lo  = min(max(bi, 0), DIM - 1);
    hi  = min(max(bi + 1, 0), DIM - 1);
    wlo = v0 ? (1.0f - w) : 0.0f;
    whi = v1 ? w : 0.0f;
}

// entry-based (w dim of duo layout): entry holds cells (e, e+1 clamped)
__device__ __forceinline__ void coord_1d_q(float r, float mn, float mx, int& e,
                                           float& wa, float& wb) {
    float t     = (r - mn) / (mx - mn);
    float ind   = t * 2.0f - 1.0f;
    float coord = (ind + 1.0f) * 0.5f * (float)(DIM - 1);
    float b  = floorf(coord);
    int   bi = (int)b;
    float w  = coord - b;
    bool v0 = (bi >= 0) && (bi < DIM);
    e  = min(max(bi, 0), DIM - 1);
    wa = v0 ? (1.0f - w) : ((bi == -1) ? w : 0.0f);
    wb = (v0 && (bi < DIM - 1)) ? w : 0.0f;
}

__device__ __forceinline__ int q8(float x) {
    float q = rintf(x * QSCALE);
    q = fminf(fmaxf(q, -127.0f), 127.0f);
    return (int)q;
}

__device__ __forceinline__ unsigned int pack4(float a, float b, float c, float d) {
    return  (unsigned int)(q8(a) & 0xFF)
         | ((unsigned int)(q8(b) & 0xFF) << 8)
         | ((unsigned int)(q8(c) & 0xFF) << 16)
         | ((unsigned int)(q8(d) & 0xFF) << 24);
}

// ---------------- fused convert: grid (C,P) f32 -> duo-w/paired-z int8 layout ----------------
// 64-B line L = ((x*48+y)*24 + zh)*48 + ew holds 4 cells:
//   uint4 sub s = (zc&1)*2 + dw  ->  cell (z = 2*zh + (zc&1), w = min(ew+dw,47)), 16 int8 ch.
// Stage 1 loads are NON-TEMPORAL: the f32 grid is single-use streaming data; nt bypasses
// L2/L3 allocation so the read stream stops churning cache tags against the write stream.
// Stores stay cached (gather needs the duo grid L3-resident).
__global__ __launch_bounds__(256) void convert_duo_lds_kernel(
    const float* __restrict__ grid,
    uint4* __restrict__ ws)
{
    // bijective XCD-chunk swizzle: NCONV % 8 == 0
    int bid = (int)blockIdx.x;
    bid = (bid & 7) * (NCONV >> 3) + (bid >> 3);

    int zb = bid % ZBLKS;
    int xy = bid / ZBLKS;
    int y  = xy % DIM;
    int x  = xy / DIM;
    int z0 = zb * ZB;
    int xy48 = (x * DIM + y) * DIM;

    __shared__ uint4 qv[ZB * WST];             // 12544 B
    unsigned int* qw = (unsigned int*)qv;

    // ---- stage 1: items (ri, wq, cq), cq fastest; 3072 = 256*12 exactly ----
    const int NITEM = ZB * 12 * 4;
    for (int it = (int)threadIdx.x; it < NITEM; it += 256) {
        int cq = it & 3;
        int t1 = it >> 2;
        int wq = t1 % 12;
        int ri = t1 / 12;                      // 0..15, zg always in range
        int zg = z0 + ri;

        const float* gp = grid + (size_t)(4 * cq) * P_TOT
                               + (size_t)(xy48 + zg) * DIM + 4 * wq;
        f32x4 v0 = __builtin_nontemporal_load((const f32x4*)(gp));
        f32x4 v1 = __builtin_nontemporal_load((const f32x4*)(gp + (size_t)P_TOT));
        f32x4 v2 = __builtin_nontemporal_load((const f32x4*)(gp + (size_t)2 * P_TOT));
        f32x4 v3 = __builtin_nontemporal_load((const f32x4*)(gp + (size_t)3 * P_TOT));

        unsigned int wd0 = pack4(v0.x, v1.x, v2.x, v3.x);
        unsigned int wd1 = pack4(v0.y, v1.y, v2.y, v3.y);
        unsigned int wd2 = pack4(v0.z, v1.z, v2.z, v3.z);
        unsigned int wd3 = pack4(v0.w, v1.w, v2.w, v3.w);

        int Abase = ri * WST + 4 * wq;
        qw[lds_swz(Abase + 0) * 4 + cq] = wd0;
        qw[lds_swz(Abase + 1) * 4 + cq] = wd1;
        qw[lds_swz(Abase + 2) * 4 + cq] = wd2;
        qw[lds_swz(Abase + 3) * 4 + cq] = wd3;
    }
    __syncthreads();

    // ---- stage 2: compose duo lines, contiguous coalesced 16B stores (cached) ----
    const int NOUT = (ZB / 2) * DIM * 4;       // 1536 uint4
    size_t ubase = (size_t)((x * DIM + y) * (DIM / 2) + (z0 >> 1)) * (DIM * 4);
    for (int idx = (int)threadIdx.x; idx < NOUT; idx += 256) {
        int zh_loc = idx / 192;                // 192 = 48*4
        int r      = idx - zh_loc * 192;
        int ew     = r >> 2;
        int sub    = r & 3;
        int zc_loc = (zh_loc << 1) | (sub >> 1);
        int wsrc   = min(ew + (sub & 1), DIM - 1);
        int A      = zc_loc * WST + wsrc;
        ws[ubase + idx] = qv[lds_swz(A)];
    }
}

// ---------------- int8 cell accumulate ----------------
__device__ __forceinline__ void accum_cell(const uint4& cell, float wc, float* acc) {
#pragma unroll
    for (int j = 0; j < 4; ++j) {
        unsigned int u = (&cell.x)[j];
        acc[4 * j + 0] += (float)((int)(u << 24) >> 24) * wc;
        acc[4 * j + 1] += (float)((int)(u << 16) >> 24) * wc;
        acc[4 * j + 2] += (float)((int)(u <<  8) >> 24) * wc;
        acc[4 * j + 3] += (float)((int)u         >> 24) * wc;
    }
}

// ---------------- gather: duo layout, 6 expected 64B lines per ray ----------------
__global__ __launch_bounds__(256) void gather_duo_kernel(
    const float4* __restrict__ ray,
    const uint4* __restrict__ gq,
    const float* __restrict__ ray_min,
    const float* __restrict__ ray_max,
    float* __restrict__ out,
    int n_rays)
{
    int n = blockIdx.x * 256 + threadIdx.x;
    if (n >= n_rays) return;

    float4 r4 = ray[n];

    int   i0x, i1x, i0y, i1y, i0z, i1z;
    float w0x, w1x, w0y, w1y, w0z, w1z;
    coord_1d(r4.x, ray_min[0], ray_max[0], i0x, i1x, w0x, w1x);
    coord_1d(r4.y, ray_min[1], ray_max[1], i0y, i1y, w0y, w1y);
    coord_1d(r4.z, ray_min[2], ray_max[2], i0z, i1z, w0z, w1z);

    int ew;
    float waw, wbw;
    coord_1d_q(r4.w, ray_min[3], ray_max[3], ew, waw, wbw);

    int zo0 = (i0z >> 1) * (DIM * 4) + (ew << 2) + ((i0z & 1) << 1);
    int zo1 = (i1z >> 1) * (DIM * 4) + (ew << 2) + ((i1z & 1) << 1);

    float acc[C_CH];
#pragma unroll
    for (int c = 0; c < C_CH; ++c) acc[c] = 0.0f;

#pragma unroll
    for (int cx = 0; cx < 2; ++cx) {
        int   x  = cx ? i1x : i0x;
        float fx = (cx ? w1x : w0x) * QINV;   // fold int8 scale into weight
#pragma unroll
        for (int cy = 0; cy < 2; ++cy) {
            int   y   = cy ? i1y : i0y;
            float fxy = fx * (cy ? w1y : w0y);
            int lb = (x * DIM + y) * (DIM / 2) * (DIM * 4);  // uint4 base of (x,y) panel

            int u0 = lb + zo0;
            uint4 a0 = gq[u0];
            uint4 b0 = gq[u0 + 1];
            float f0 = fxy * w0z;
            accum_cell(a0, f0 * waw, acc);
            accum_cell(b0, f0 * wbw, acc);

            int u1 = lb + zo1;
            uint4 a1 = gq[u1];
            uint4 b1 = gq[u1 + 1];
            float f1 = fxy * w1z;
            accum_cell(a1, f1 * waw, acc);
            accum_cell(b1, f1 * wbw, acc);
        }
    }

    float4* o = reinterpret_cast<float4*>(out + (size_t)n * C_CH);
    o[0] = make_float4(acc[0],  acc[1],  acc[2],  acc[3]);
    o[1] = make_float4(acc[4],  acc[5],  acc[6],  acc[7]);
    o[2] = make_float4(acc[8],  acc[9],  acc[10], acc[11]);
    o[3] = make_float4(acc[12], acc[13], acc[14], acc[15]);
}

// ---------------- mid fallback: tiled int8 (2x2x2 of y,z,w), 16 B per cell ----------------
__global__ __launch_bounds__(256) void convert_tiled_kernel(
    const float* __restrict__ grid,
    uint4* __restrict__ ws)
{
    int t = blockIdx.x * 256 + threadIdx.x;
    if (t >= P_TOT) return;

    int intra = t & 7;
    int line  = t >> 3;
    int wh = line % 24;  int r1 = line / 24;
    int zh = r1 % 24;    int r2 = r1 / 24;
    int yh = r2 % 24;    int x  = r2 / 24;
    int wl = intra & 1, zl = (intra >> 1) & 1, yl = (intra >> 2) & 1;
    int y = yh * 2 + yl, z = zh * 2 + zl, w = wh * 2 + wl;
    int p = ((x * DIM + y) * DIM + z) * DIM + w;

    unsigned int pk[4];
#pragma unroll
    for (int j = 0; j < 4; ++j) {
        unsigned int b0 = (unsigned int)(q8(grid[(size_t)(4 * j + 0) * P_TOT + p]) & 0xFF);
        unsigned int b1 = (unsigned int)(q8(grid[(size_t)(4 * j + 1) * P_TOT + p]) & 0xFF);
        unsigned int b2 = (unsigned int)(q8(grid[(size_t)(4 * j + 2) * P_TOT + p]) & 0xFF);
        unsigned int b3 = (unsigned int)(q8(grid[(size_t)(4 * j + 3) * P_TOT + p]) & 0xFF);
        pk[j] = b0 | (b1 << 8) | (b2 << 16) | (b3 << 24);
    }
    ws[t] = make_uint4(pk[0], pk[1], pk[2], pk[3]);
}

__global__ __launch_bounds__(256) void gather_tiled_kernel(
    const float4* __restrict__ ray,
    const uint4* __restrict__ gq,
    const float* __restrict__ ray_min,
    const float* __restrict__ ray_max,
    float* __restrict__ out,
    int n_rays)
{
    int n = blockIdx.x * 256 + threadIdx.x;
    if (n >= n_rays) return;

    float4 r4 = ray[n];
    float rr[4] = {r4.x, r4.y, r4.z, r4.w};

    int   i0[4], i1[4];
    float w0[4], w1[4];
#pragma unroll
    for (int d = 0; d < 4; ++d)
        coord_1d(rr[d], ray_min[d], ray_max[d], i0[d], i1[d], w0[d], w1[d]);

    float acc[C_CH];
#pragma unroll
    for (int c = 0; c < C_CH; ++c) acc[c] = 0.0f;

#pragma unroll
    for (int cx = 0; cx < 2; ++cx) {
        int   x  = cx ? i1[0] : i0[0];
        float fx = (cx ? w1[0] : w0[0]) * QINV;
        int bx = x * 24;
#pragma unroll
        for (int cy = 0; cy < 2; ++cy) {
            int   y   = cy ? i1[1] : i0[1];
            float fxy = fx * (cy ? w1[1] : w0[1]);
            int ly = (bx + (y >> 1)) * 24;
            int iy = (y & 1) << 2;
#pragma unroll
            for (int cz = 0; cz < 2; ++cz) {
                int   z    = cz ? i1[2] : i0[2];
                float fxyz = fxy * (cz ? w1[2] : w0[2]);
                int lz = (ly + (z >> 1)) * 24;
                int iz = iy | ((z & 1) << 1);
#pragma unroll
                for (int cw = 0; cw < 2; ++cw) {
                    int   w  = cw ? i1[3] : i0[3];
                    float wc = fxyz * (cw ? w1[3] : w0[3]);
                    int cellidx = ((lz + (w >> 1)) << 3) | iz | (w & 1);
                    uint4 cell = gq[cellidx];
                    accum_cell(cell, wc, acc);
                }
            }
        }
    }

    float4* o = reinterpret_cast<float4*>(out + (size_t)n * C_CH);
    o[0] = make_float4(acc[0],  acc[1],  acc[2],  acc[3]);
    o[1] = make_float4(acc[4],  acc[5],  acc[6],  acc[7]);
    o[2] = make_float4(acc[8],  acc[9],  acc[10], acc[11]);
    o[3] = make_float4(acc[12], acc[13], acc[14], acc[15]);
}

// ---------------- f32 fallback if ws too small ----------------
__global__ __launch_bounds__(256) void lf4d_gather_kernel(
    const float4* __restrict__ ray,
    const float* __restrict__ grid,
    const float* __restrict__ ray_min,
    const float* __restrict__ ray_max,
    float* __restrict__ out,
    int n_rays)
{
    int n = blockIdx.x * 256 + threadIdx.x;
    if (n >= n_rays) return;
    float4 r4 = ray[n];
    float rr[4] = {r4.x, r4.y, r4.z, r4.w};
    int   i0[4], i1[4];
    float w0[4], w1[4];
#pragma unroll
    for (int d = 0; d < 4; ++d)
        coord_1d(rr[d], ray_min[d], ray_max[d], i0[d], i1[d], w0[d], w1[d]);
    float acc[C_CH];
#pragma unroll
    for (int c = 0; c < C_CH; ++c) acc[c] = 0.0f;
    const int s0 = DIM * DIM * DIM, s1 = DIM * DIM, s2 = DIM;
#pragma unroll
    for (int k = 0; k < 8; ++k) {
        int   x  = (k & 1) ? i1[0] : i0[0];
        float wx = (k & 1) ? w1[0] : w0[0];
        int   y  = (k & 2) ? i1[1] : i0[1];
        float wy = (k & 2) ? w1[1] : w0[1];
        int   z  = (k & 4) ? i1[2] : i0[2];
        float wz = (k & 4) ? w1[2] : w0[2];
        int   base = x * s0 + y * s1 + z * s2;
        float wxyz = wx * wy * wz;
        float wa = wxyz * w0[3], wb = wxyz * w1[3];
        int ia = base + i0[3], ib = base + i1[3];
#pragma unroll
        for (int c = 0; c < C_CH; ++c) {
            float va = grid[c * P_TOT + ia];
            float vb = grid[c * P_TOT + ib];
            acc[c] += va * wa + vb * wb;
        }
    }
    float4* o = reinterpret_cast<float4*>(out + (size_t)n * C_CH);
    o[0] = make_float4(acc[0],  acc[1],  acc[2],  acc[3]);
    o[1] = make_float4(acc[4],  acc[5],  acc[6],  acc[7]);
    o[2] = make_float4(acc[8],  acc[9],  acc[10], acc[11]);
    o[3] = make_float4(acc[12], acc[13], acc[14], acc[15]);
}

extern "C" void kernel_launch(void* const* d_in, const int* in_sizes, int n_in,
                              void* d_out, int out_size, void* d_ws, size_t ws_size,
                              hipStream_t stream) {
    const float4* ray     = (const float4*)d_in[0];
    const float*  grid    = (const float*)d_in[1];
    const float*  ray_min = (const float*)d_in[2];
    const float*  ray_max = (const float*)d_in[3];
    float*        out     = (float*)d_out;

    int n_rays  = in_sizes[0] / 4;
    int rblocks = (n_rays + 255) / 256;

    const size_t duo_bytes   = (size_t)P_TOT * 32;  // ~170 MiB
    const size_t tiled_bytes = (size_t)P_TOT * 16;  // ~81 MiB

    if (ws_size >= duo_bytes) {
        uint4* gq = (uint4*)d_ws;
        convert_duo_lds_kernel<<<NCONV, 256, 0, stream>>>(grid, gq);
        gather_duo_kernel<<<rblocks, 256, 0, stream>>>(
            ray, (const uint4*)gq, ray_min, ray_max, out, n_rays);
    } else if (ws_size >= tiled_bytes) {
        uint4* gq = (uint4*)d_ws;
        int tblocks = (P_TOT + 255) / 256;
        convert_tiled_kernel<<<tblocks, 256, 0, stream>>>(grid, gq);
        gather_tiled_kernel<<<rblocks, 256, 0, stream>>>(
            ray, (const uint4*)gq, ray_min, ray_max, out, n_rays);
    } else {
        lf4d_gather_kernel<<<rblocks, 256, 0, stream>>>(ray, grid, ray_min, ray_max, out, n_rays);
    }
}